// Round 14
// baseline (86.252 us; speedup 1.0000x reference)
//
#include <hip/hip_runtime.h>
#include <hip/hip_bf16.h>

typedef __attribute__((ext_vector_type(8))) short short8;
typedef __attribute__((ext_vector_type(4))) float f32x4;

static constexpr int IN = 32, OUT = 32, DYNDIM = 16, KNBR = 7;
static constexpr int ROWS = 512;              // rows per tile
static constexpr int PAD  = 192;              // max |nbr - n| = 191 < 192
static constexpr int WIN  = ROWS + 2 * PAD;   // 896-row window
static constexpr int LROW = 36;               // shorts per LDS row (32 + 4 pad)
static constexpr int BUFR = WIN + 1;          // + zero row at slot WIN
static constexpr int NT   = 512;              // 8 waves
static constexpr int NBGRP = 8;               // batches per persistent block
static constexpr int LDS_BYTES = 2 * BUFR * LROW * 2;   // 129168 B (double buffer)

__device__ inline unsigned short f2bf(float f) {
    unsigned u = __builtin_bit_cast(unsigned, f);
    unsigned r = (u + 0x7fffu + ((u >> 16) & 1u)) >> 16;   // RNE
    return (unsigned short)r;
}
__device__ inline unsigned cvtpk(float lo, float hi) {
    unsigned r;
    asm("v_cvt_pk_bf16_f32 %0, %1, %2" : "=v"(r) : "v"(lo), "v"(hi));
    return r;
}

// ---------- Kernel 1: combined weights, bf16, paired-col B-fragment layout ----------
// ch = o&1, cc = o>>1; Wp[b][k][ch][lane][j], lane=(i>>3)*16+cc, j=i&7
__global__ void pack_weights(const float* __restrict__ dyn,
                             const float* __restrict__ Wdyn,
                             const float* __restrict__ Wstat,
                             unsigned short* __restrict__ Wp)
{
    int bk = blockIdx.x;              // b*7 + k
    int k  = bk % KNBR;
    __shared__ float dsh[DYNDIM];
    if (threadIdx.x < DYNDIM)
        dsh[threadIdx.x] = dyn[(size_t)bk * DYNDIM + threadIdx.x];
    __syncthreads();

    for (int e = threadIdx.x; e < IN * OUT; e += blockDim.x) {
        int i = e >> 5, o = e & 31;
        float acc = Wstat[((size_t)k * IN + i) * OUT + o];
        const float* wd = Wdyn + (((size_t)k * DYNDIM) * IN + i) * OUT + o;
#pragma unroll
        for (int d = 0; d < DYNDIM; ++d)
            acc += dsh[d] * wd[(size_t)d * IN * OUT];
        int ch = o & 1, cc = o >> 1, g = i >> 3, j = i & 7;
        Wp[(((size_t)bk * 2 + ch) * 64 + (g * 16 + cc)) * 8 + j] = f2bf(acc);
    }
}

// ---------- persistent pipelined main kernel ----------
// One block = (bx, 8 batches). Double-buffered window; per step:
// [bw(b) loads][window(b+1) loads] -> compute(b) from buf RB -> cvt+ds_write buf WB -> barrier.
struct StepArgs {
    const float* grid; const unsigned short* Wp; const float* bias; float* out;
    const unsigned short* glds; int N; int win_lo; int wbase; int lane, g, c;
    float bc0, bc1; int srow0, sseg;
};

template<int RB, int WB>
__device__ __forceinline__ void pipe_step(const StepArgs& A, unsigned short* glds,
                                          const int off[4][KNBR], int b, bool pre)
{
    // 1) bw(b) — issued FIRST so compute waits vmcnt(14), not 0
    const unsigned short* wpb = A.Wp + (size_t)b * KNBR * 1024;
    short8 bw[KNBR][2];
#pragma unroll
    for (int kk = 0; kk < KNBR; ++kk)
#pragma unroll
        for (int ch = 0; ch < 2; ++ch)
            bw[kk][ch] = *(const short8*)(wpb + ((size_t)(kk * 2 + ch) * 64 + A.lane) * 8);

    // 2) window(b+1) prefetch into held registers (in flight across compute)
    float4 hlo[7], hhi[7];
    if (pre) {
        const float* gb = A.grid + (size_t)(b + 1) * A.N * 32;
#pragma unroll
        for (int it = 0; it < 7; ++it) {
            hlo[it] = make_float4(0.f, 0.f, 0.f, 0.f);
            hhi[it] = make_float4(0.f, 0.f, 0.f, 0.f);
            int gr = A.win_lo + A.srow0 + it * 128;
            if (gr >= 0 && gr < A.N) {
                const float* gp = gb + (size_t)gr * 32 + A.sseg * 8;
                hlo[it] = *(const float4*)gp;
                hhi[it] = *(const float4*)(gp + 4);
            }
        }
    }

    // 3) compute batch b from buffer RB (no global waits besides bw)
    const size_t obase = (size_t)b * A.N * 32;
#pragma unroll
    for (int t = 0; t < 4; ++t) {
        f32x4 a0 = {0.f, 0.f, 0.f, 0.f};
        f32x4 a1 = {0.f, 0.f, 0.f, 0.f};
#pragma unroll
        for (int kk = 0; kk < KNBR; ++kk) {
            const short8 av = *(const short8*)(glds + RB * BUFR * LROW +
                                               (size_t)off[t][kk] * LROW + A.g * 8);
            a0 = __builtin_amdgcn_mfma_f32_16x16x32_bf16(av, bw[kk][0], a0, 0, 0, 0);
            a1 = __builtin_amdgcn_mfma_f32_16x16x32_bf16(av, bw[kk][1], a1, 0, 0, 0);
        }
        const int row_base = A.wbase + t * 16 + A.g * 4;
#pragma unroll
        for (int r = 0; r < 4; ++r) {
            int row = row_base + r;
            if (row < A.N) {
                float* op = A.out + obase + (size_t)row * 32;
                float2 v2; v2.x = a0[r] + A.bc0; v2.y = a1[r] + A.bc1;
                __builtin_nontemporal_store(
                    __builtin_bit_cast(unsigned long long, v2),
                    (unsigned long long*)(op + 2 * A.c));
            }
        }
    }

    // 4) drain holds, cvt, write buffer WB
    if (pre) {
#pragma unroll
        for (int it = 0; it < 7; ++it) {
            uint4 vv;
            vv.x = cvtpk(hlo[it].x, hlo[it].y);
            vv.y = cvtpk(hlo[it].z, hlo[it].w);
            vv.z = cvtpk(hhi[it].x, hhi[it].y);
            vv.w = cvtpk(hhi[it].z, hhi[it].w);
            *(uint4*)(glds + WB * BUFR * LROW +
                      (A.srow0 + it * 128) * LROW + A.sseg * 8) = vv;
        }
    }
    __syncthreads();
}

__global__ __launch_bounds__(NT, 2) void hexconv_pipe(
    const float* __restrict__ grid, const int* __restrict__ nbr,
    const unsigned short* __restrict__ Wp, const float* __restrict__ bias,
    float* __restrict__ out, int N)
{
    extern __shared__ unsigned short glds[];

    const int nwg = gridDim.x;
    int orig = blockIdx.x, wg = orig;
    if ((nwg & 7) == 0) { int cpx = nwg >> 3; wg = (orig & 7) * cpx + (orig >> 3); }
    const int NBX = (N + ROWS - 1) / ROWS;
    const int bx = wg % NBX;
    const int b0 = (wg / NBX) * NBGRP;

    const int base = bx * ROWS, win_lo = base - PAD;
    const int lane = threadIdx.x & 63, w = threadIdx.x >> 6;
    const int g = lane >> 4, c = lane & 15;
    const int wbase = base + w * 64;
    const int srow0 = threadIdx.x >> 2, sseg = threadIdx.x & 3;

    // batch-invariant window offsets (7 idx loads per t, once per block)
    int off[4][KNBR];
#pragma unroll
    for (int t = 0; t < 4; ++t) {
        int n0 = wbase + t * 16 + c;
        bool v = (n0 < N);
#pragma unroll
        for (int kk = 0; kk < KNBR; ++kk) {
            int id = (kk == 3) ? (v ? n0 : -1)
                               : (v ? nbr[(size_t)kk * N + n0] : -1);
            off[t][kk] = (id < 0) ? WIN : (id - win_lo);
        }
    }

    // zero rows for both buffers
    if (threadIdx.x < 18) {
        ((unsigned*)(glds + WIN * LROW))[threadIdx.x] = 0;
        ((unsigned*)(glds + (BUFR + WIN) * LROW))[threadIdx.x] = 0;
    }

    // prologue: stage batch b0 into buffer 0 (head paid once per 8 tiles)
    {
        const float* gb = grid + (size_t)b0 * N * 32;
#pragma unroll
        for (int it = 0; it < 7; ++it) {
            float4 x0 = make_float4(0.f, 0.f, 0.f, 0.f);
            float4 x1 = make_float4(0.f, 0.f, 0.f, 0.f);
            int gr = win_lo + srow0 + it * 128;
            if (gr >= 0 && gr < N) {
                const float* gp = gb + (size_t)gr * 32 + sseg * 8;
                x0 = *(const float4*)gp; x1 = *(const float4*)(gp + 4);
            }
            uint4 vv;
            vv.x = cvtpk(x0.x, x0.y); vv.y = cvtpk(x0.z, x0.w);
            vv.z = cvtpk(x1.x, x1.y); vv.w = cvtpk(x1.z, x1.w);
            *(uint4*)(glds + (srow0 + it * 128) * LROW + sseg * 8) = vv;
        }
    }
    __syncthreads();

    StepArgs A{grid, Wp, bias, out, glds, N, win_lo, wbase, lane, g, c,
               bias[2 * c], bias[2 * c + 1], srow0, sseg};

#pragma unroll 1
    for (int jp = 0; jp < NBGRP / 2; ++jp) {
        int j0 = 2 * jp;
        pipe_step<0, 1>(A, glds, off, b0 + j0, true);
        pipe_step<1, 0>(A, glds, off, b0 + j0 + 1, (j0 + 1) < NBGRP - 1);
    }
}

// ---------- fallback (R12 single-tile kernel, shares pack layout) ----------
__global__ __launch_bounds__(NT, 4) void hexconv_fused(
    const float* __restrict__ grid, const int* __restrict__ nbr,
    const unsigned short* __restrict__ Wp, const float* __restrict__ bias,
    float* __restrict__ out, int N)
{
    __shared__ unsigned short slds[BUFR * LROW];
    const int nwgx = gridDim.x;
    const int nwg  = nwgx * gridDim.y;
    int orig = blockIdx.x + nwgx * blockIdx.y, wg = orig;
    if ((nwg & 7) == 0) { int cpx = nwg >> 3; wg = (orig & 7) * cpx + (orig >> 3); }
    const int bx = wg % nwgx, b = wg / nwgx;
    const int base = bx * ROWS, win_lo = base - PAD;
    const size_t gbase = (size_t)b * N * 32;
    const int lane = threadIdx.x & 63, w = threadIdx.x >> 6;
    const int g = lane >> 4, c = lane & 15;
    const int wbase = base + w * 64;

    const unsigned short* wpb = Wp + (size_t)b * KNBR * 1024;
    short8 bw[KNBR][2];
#pragma unroll
    for (int kk = 0; kk < KNBR; ++kk)
#pragma unroll
        for (int ch = 0; ch < 2; ++ch)
            bw[kk][ch] = *(const short8*)(wpb + ((size_t)(kk * 2 + ch) * 64 + lane) * 8);

    int off[4][KNBR];
#pragma unroll
    for (int t = 0; t < 4; ++t) {
        int n0 = wbase + t * 16 + c;
        bool v = (n0 < N);
#pragma unroll
        for (int kk = 0; kk < KNBR; ++kk) {
            int id = (kk == 3) ? (v ? n0 : -1) : (v ? nbr[(size_t)kk * N + n0] : -1);
            off[t][kk] = (id < 0) ? WIN : (id - win_lo);
        }
    }
    if (threadIdx.x < 18)
        ((unsigned*)(slds + WIN * LROW))[threadIdx.x] = 0;

    for (int e = threadIdx.x; e < WIN * 4; e += NT) {
        int row = e >> 2, seg = e & 3, gr = win_lo + row;
        if (gr >= 0 && gr < N) {
            const float* gp = grid + gbase + (size_t)gr * 32 + seg * 8;
            float4 x0 = *(const float4*)gp, x1 = *(const float4*)(gp + 4);
            uint4 vv;
            vv.x = cvtpk(x0.x, x0.y); vv.y = cvtpk(x0.z, x0.w);
            vv.z = cvtpk(x1.x, x1.y); vv.w = cvtpk(x1.z, x1.w);
            *(uint4*)(slds + row * LROW + seg * 8) = vv;
        }
    }
    __syncthreads();

    const float bc0 = bias[2 * c], bc1 = bias[2 * c + 1];
#pragma unroll
    for (int t = 0; t < 4; ++t) {
        f32x4 a0 = {0.f, 0.f, 0.f, 0.f}, a1 = {0.f, 0.f, 0.f, 0.f};
#pragma unroll
        for (int kk = 0; kk < KNBR; ++kk) {
            short8 av = *(const short8*)(slds + (size_t)off[t][kk] * LROW + g * 8);
            a0 = __builtin_amdgcn_mfma_f32_16x16x32_bf16(av, bw[kk][0], a0, 0, 0, 0);
            a1 = __builtin_amdgcn_mfma_f32_16x16x32_bf16(av, bw[kk][1], a1, 0, 0, 0);
        }
        const int row_base = wbase + t * 16 + g * 4;
#pragma unroll
        for (int r = 0; r < 4; ++r) {
            int row = row_base + r;
            if (row < N) {
                float* op = out + gbase + (size_t)row * 32;
                float2 v2; v2.x = a0[r] + bc0; v2.y = a1[r] + bc1;
                __builtin_nontemporal_store(
                    __builtin_bit_cast(unsigned long long, v2),
                    (unsigned long long*)(op + 2 * c));
            }
        }
    }
}

extern "C" void kernel_launch(void* const* d_in, const int* in_sizes, int n_in,
                              void* d_out, int out_size, void* d_ws, size_t ws_size,
                              hipStream_t stream)
{
    const float* grid  = (const float*)d_in[0];
    const float* dyn   = (const float*)d_in[1];
    const int*   nbr   = (const int*)d_in[2];
    const float* Wdyn  = (const float*)d_in[3];
    const float* Wstat = (const float*)d_in[4];
    const float* bias  = (const float*)d_in[5];
    float* out = (float*)d_out;

    const int N = in_sizes[2] / KNBR;               // 27361
    const int B = in_sizes[0] / (N * IN);           // 32

    unsigned short* Wp = (unsigned short*)d_ws;     // B*7*1024 bf16 = 458752 B
    pack_weights<<<B * KNBR, 256, 0, stream>>>(dyn, Wdyn, Wstat, Wp);

    const int NBX = (N + ROWS - 1) / ROWS;          // 54
    static bool attr_ok = []() {
        return hipFuncSetAttribute((const void*)hexconv_pipe,
                                   hipFuncAttributeMaxDynamicSharedMemorySize,
                                   LDS_BYTES) == hipSuccess;
    }();

    if (attr_ok && (B % NBGRP) == 0) {
        int blocks = NBX * (B / NBGRP);             // 216
        hexconv_pipe<<<blocks, NT, LDS_BYTES, stream>>>(grid, nbr, Wp, bias, out, N);
    } else {
        dim3 grd(NBX, B);
        hexconv_fused<<<grd, NT, 0, stream>>>(grid, nbr, Wp, bias, out, N);
    }
}

// Round 15
// 55.770 us; speedup vs baseline: 1.5466x; 1.5466x over previous
//
#include <hip/hip_runtime.h>
#include <hip/hip_bf16.h>

typedef __attribute__((ext_vector_type(8))) short short8;
typedef __attribute__((ext_vector_type(4))) float f32x4;

static constexpr int IN = 32, OUT = 32, DYNDIM = 16, KNBR = 7;
static constexpr int ROWS = 512;              // rows per block
static constexpr int PAD  = 192;              // max |nbr - n| = 191 < 192
static constexpr int WIN  = ROWS + 2 * PAD;   // 896-row staged window
static constexpr int LROW = 36;               // shorts per LDS row (32 + 4 pad)
static constexpr int NT   = 512;              // threads per block (8 waves)

__device__ inline unsigned short f2bf(float f) {
    unsigned u = __builtin_bit_cast(unsigned, f);
    unsigned r = (u + 0x7fffu + ((u >> 16) & 1u)) >> 16;   // RNE
    return (unsigned short)r;
}

__device__ inline short8 cvt8(float4 lo, float4 hi) {
    short8 v;
    v[0] = (short)f2bf(lo.x); v[1] = (short)f2bf(lo.y);
    v[2] = (short)f2bf(lo.z); v[3] = (short)f2bf(lo.w);
    v[4] = (short)f2bf(hi.x); v[5] = (short)f2bf(hi.y);
    v[6] = (short)f2bf(hi.z); v[7] = (short)f2bf(hi.w);
    return v;
}

// ---------- Kernel 1: combined weights, bf16, B-fragment layout ----------
// Wp[b][k][ch][lane][j], lane=(i>>3)*16+(o&15), j=i&7
__global__ void pack_weights(const float* __restrict__ dyn,
                             const float* __restrict__ Wdyn,
                             const float* __restrict__ Wstat,
                             unsigned short* __restrict__ Wp)
{
    int bk = blockIdx.x;              // b*7 + k
    int k  = bk % KNBR;
    __shared__ float dsh[DYNDIM];
    if (threadIdx.x < DYNDIM)
        dsh[threadIdx.x] = dyn[(size_t)bk * DYNDIM + threadIdx.x];
    __syncthreads();

    for (int e = threadIdx.x; e < IN * OUT; e += blockDim.x) {
        int i = e >> 5, o = e & 31;
        float acc = Wstat[((size_t)k * IN + i) * OUT + o];
        const float* wd = Wdyn + (((size_t)k * DYNDIM) * IN + i) * OUT + o;
#pragma unroll
        for (int d = 0; d < DYNDIM; ++d)
            acc += dsh[d] * wd[(size_t)d * IN * OUT];
        int ch = o >> 4, cc = o & 15, g = i >> 3, j = i & 7;
        Wp[(((size_t)bk * 2 + ch) * 64 + (g * 16 + cc)) * 8 + j] = f2bf(acc);
    }
}

// ---------- Kernel 2 (fused main) ----------
// R9 structure (512 thr, 512 rows, 2 blocks/CU, reg-B, idx pipeline, XCD
// swizzle, nontemporal stores) + R15: depth-4 rolling-prefetch stage.
__global__ __launch_bounds__(NT, 4) void hexconv_fused(
    const float* __restrict__ grid,        // (B,N,32) f32
    const int* __restrict__ nbr,           // (7,N)
    const unsigned short* __restrict__ Wp, // (B,7,2,64,8) bf16
    const float* __restrict__ bias,        // (32)
    float* __restrict__ out,               // (B,N,32) f32
    int N)
{
    __shared__ unsigned short glds[WIN * LROW];   // 64512 B

    // XCD-chunked bijective remap (nwg % 8 == 0 for the real shape)
    const int nwgx = gridDim.x;
    const int nwg  = nwgx * gridDim.y;
    int orig = blockIdx.x + nwgx * blockIdx.y;
    int wg = orig;
    if ((nwg & 7) == 0) {
        int cpx = nwg >> 3;
        wg = (orig & 7) * cpx + (orig >> 3);
    }
    const int bx = wg % nwgx;
    const int b  = wg / nwgx;

    const int base   = bx * ROWS;
    const int win_lo = base - PAD;
    const size_t gbase = (size_t)b * N * 32;

    const int lane = threadIdx.x & 63;
    const int w    = threadIdx.x >> 6;          // wave 0..7
    const int g    = lane >> 4;
    const int c    = lane & 15;
    const int wbase = base + w * 64;            // 64 rows per wave

    // B fragments -> registers (issued first; complete under staging)
    const unsigned short* wpb = Wp + (size_t)b * KNBR * 1024;
    short8 bw[KNBR][2];
#pragma unroll
    for (int kk = 0; kk < KNBR; ++kk)
#pragma unroll
        for (int ch = 0; ch < 2; ++ch)
            bw[kk][ch] = *(const short8*)(wpb + ((size_t)(kk * 2 + ch) * 64 + lane) * 8);

    // t=0 neighbor indices, issued before staging (hidden under it)
    int idxc[KNBR];
    {
        const int n0 = wbase + c;
        const bool v = (n0 < N);
#pragma unroll
        for (int kk = 0; kk < KNBR; ++kk) {
            if (kk == 3) idxc[kk] = v ? n0 : -1;         // center: nbr[3,n] == n
            else         idxc[kk] = v ? nbr[(size_t)kk * N + n0] : -1;
        }
    }

    // ---- stage grid window: depth-4 rolling prefetch (interior fast path) ----
    const int  srow = threadIdx.x >> 2;          // 0..127
    const int  sseg = threadIdx.x & 3;
    const bool interior = (win_lo >= 0) && (win_lo + WIN <= N);
    if (interior) {
        const float* gp0 = grid + gbase + (size_t)win_lo * 32 + sseg * 8;
        float4 plo[4], phi[4];
#pragma unroll
        for (int p = 0; p < 4; ++p) {            // pre-issue rounds 0..3
            const float* gp = gp0 + (size_t)(srow + p * 128) * 32;
            plo[p] = *(const float4*)gp;
            phi[p] = *(const float4*)(gp + 4);
        }
#pragma unroll
        for (int it = 0; it < 7; ++it) {         // consume it, issue it+4
            int row = srow + it * 128;
            *(short8*)(glds + row * LROW + sseg * 8) = cvt8(plo[it & 3], phi[it & 3]);
            if (it + 4 < 7) {
                const float* gp = gp0 + (size_t)(srow + (it + 4) * 128) * 32;
                plo[it & 3] = *(const float4*)gp;
                phi[it & 3] = *(const float4*)(gp + 4);
            }
        }
    } else {
#pragma unroll
        for (int it = 0; it < 7; ++it) {
            int row = srow + it * 128;
            int gr = win_lo + row;
            if (gr >= 0 && gr < N) {
                const float* gp = grid + gbase + (size_t)gr * 32 + sseg * 8;
                float4 lo = *(const float4*)gp;
                float4 hi = *(const float4*)(gp + 4);
                *(short8*)(glds + row * LROW + sseg * 8) = cvt8(lo, hi);
            }
        }
    }
    __syncthreads();

    const float bc0 = bias[c];
    const float bc1 = bias[16 + c];

#pragma unroll
    for (int t = 0; t < 4; ++t) {
        // prefetch next sub-tile's indices before this tile's MFMA cluster
        int idxn[KNBR];
        if (t < 3) {
            const int n1 = wbase + (t + 1) * 16 + c;
            const bool v = (n1 < N);
#pragma unroll
            for (int kk = 0; kk < KNBR; ++kk) {
                if (kk == 3) idxn[kk] = v ? n1 : -1;
                else         idxn[kk] = v ? nbr[(size_t)kk * N + n1] : -1;
            }
        }

        f32x4 acc0 = {0.f, 0.f, 0.f, 0.f};
        f32x4 acc1 = {0.f, 0.f, 0.f, 0.f};
#pragma unroll
        for (int kk = 0; kk < KNBR; ++kk) {
            short8 a = {0, 0, 0, 0, 0, 0, 0, 0};
            int id = idxc[kk];
            if (id >= 0)
                a = *(const short8*)(glds + (size_t)(id - win_lo) * LROW + g * 8);
            acc0 = __builtin_amdgcn_mfma_f32_16x16x32_bf16(a, bw[kk][0], acc0, 0, 0, 0);
            acc1 = __builtin_amdgcn_mfma_f32_16x16x32_bf16(a, bw[kk][1], acc1, 0, 0, 0);
        }

        const int row_base = wbase + t * 16 + g * 4;
#pragma unroll
        for (int r = 0; r < 4; ++r) {
            int row = row_base + r;
            if (row < N) {
                float* op = out + gbase + (size_t)row * 32;
                __builtin_nontemporal_store(acc0[r] + bc0, op + c);
                __builtin_nontemporal_store(acc1[r] + bc1, op + 16 + c);
            }
        }

        if (t < 3) {
#pragma unroll
            for (int kk = 0; kk < KNBR; ++kk) idxc[kk] = idxn[kk];
        }
    }
}

extern "C" void kernel_launch(void* const* d_in, const int* in_sizes, int n_in,
                              void* d_out, int out_size, void* d_ws, size_t ws_size,
                              hipStream_t stream)
{
    const float* grid  = (const float*)d_in[0];
    const float* dyn   = (const float*)d_in[1];
    const int*   nbr   = (const int*)d_in[2];
    const float* Wdyn  = (const float*)d_in[3];
    const float* Wstat = (const float*)d_in[4];
    const float* bias  = (const float*)d_in[5];
    float* out = (float*)d_out;

    const int N = in_sizes[2] / KNBR;               // 27361
    const int B = in_sizes[0] / (N * IN);           // 32

    unsigned short* Wp = (unsigned short*)d_ws;     // B*7*1024 bf16 = 458752 B
    pack_weights<<<B * KNBR, 256, 0, stream>>>(dyn, Wdyn, Wstat, Wp);

    dim3 grd((N + ROWS - 1) / ROWS, B);
    hexconv_fused<<<grd, NT, 0, stream>>>(grid, nbr, Wp, bias, out, N);
}

// Round 16
// 54.169 us; speedup vs baseline: 1.5923x; 1.0295x over previous
//
#include <hip/hip_runtime.h>
#include <hip/hip_bf16.h>

typedef __attribute__((ext_vector_type(8))) short short8;
typedef __attribute__((ext_vector_type(4))) float f32x4;

static constexpr int IN = 32, OUT = 32, DYNDIM = 16, KNBR = 7;
static constexpr int ROWS = 512;              // rows per block
static constexpr int PAD  = 192;              // max |nbr - n| = 191 < 192
static constexpr int WIN  = ROWS + 2 * PAD;   // 896-row staged window
static constexpr int LROW = 36;               // shorts per LDS row (32 + 4 pad)
static constexpr int NT   = 512;              // threads per block (8 waves)

__device__ inline unsigned short f2bf(float f) {
    unsigned u = __builtin_bit_cast(unsigned, f);
    unsigned r = (u + 0x7fffu + ((u >> 16) & 1u)) >> 16;   // RNE
    return (unsigned short)r;
}

// ---------- Kernel 1: combined weights, bf16, B-fragment layout ----------
// Wp[b][k][ch][lane][j], lane=(i>>3)*16+(o&15), j=i&7
__global__ void pack_weights(const float* __restrict__ dyn,
                             const float* __restrict__ Wdyn,
                             const float* __restrict__ Wstat,
                             unsigned short* __restrict__ Wp)
{
    int bk = blockIdx.x;              // b*7 + k
    int k  = bk % KNBR;
    __shared__ float dsh[DYNDIM];
    if (threadIdx.x < DYNDIM)
        dsh[threadIdx.x] = dyn[(size_t)bk * DYNDIM + threadIdx.x];
    __syncthreads();

    for (int e = threadIdx.x; e < IN * OUT; e += blockDim.x) {
        int i = e >> 5, o = e & 31;
        float acc = Wstat[((size_t)k * IN + i) * OUT + o];
        const float* wd = Wdyn + (((size_t)k * DYNDIM) * IN + i) * OUT + o;
#pragma unroll
        for (int d = 0; d < DYNDIM; ++d)
            acc += dsh[d] * wd[(size_t)d * IN * OUT];
        int ch = o >> 4, cc = o & 15, g = i >> 3, j = i & 7;
        Wp[(((size_t)bk * 2 + ch) * 64 + (g * 16 + cc)) * 8 + j] = f2bf(acc);
    }
}

// ---------- Kernel 2 (fused main) — session-best R9 configuration ----------
// f32 window -> LDS bf16; B-fragments in registers (global->reg, L2-resident);
// idx loads software-pipelined; XCD-chunked swizzle; 512 threads, 512 rows,
// 2 blocks/CU; nontemporal output stores (keep grid slice L2-resident).
__global__ __launch_bounds__(NT, 4) void hexconv_fused(
    const float* __restrict__ grid,        // (B,N,32) f32
    const int* __restrict__ nbr,           // (7,N)
    const unsigned short* __restrict__ Wp, // (B,7,2,64,8) bf16
    const float* __restrict__ bias,        // (32)
    float* __restrict__ out,               // (B,N,32) f32
    int N)
{
    __shared__ unsigned short glds[WIN * LROW];   // 64512 B

    // XCD-chunked bijective remap (nwg % 8 == 0 for the real shape)
    const int nwgx = gridDim.x;
    const int nwg  = nwgx * gridDim.y;
    int orig = blockIdx.x + nwgx * blockIdx.y;
    int wg = orig;
    if ((nwg & 7) == 0) {
        int cpx = nwg >> 3;
        wg = (orig & 7) * cpx + (orig >> 3);
    }
    const int bx = wg % nwgx;
    const int b  = wg / nwgx;

    const int base   = bx * ROWS;
    const int win_lo = base - PAD;
    const size_t gbase = (size_t)b * N * 32;

    const int lane = threadIdx.x & 63;
    const int w    = threadIdx.x >> 6;          // wave 0..7
    const int g    = lane >> 4;
    const int c    = lane & 15;
    const int wbase = base + w * 64;            // 64 rows per wave

    // B fragments -> registers (issued first; complete under staging)
    const unsigned short* wpb = Wp + (size_t)b * KNBR * 1024;
    short8 bw[KNBR][2];
#pragma unroll
    for (int kk = 0; kk < KNBR; ++kk)
#pragma unroll
        for (int ch = 0; ch < 2; ++ch)
            bw[kk][ch] = *(const short8*)(wpb + ((size_t)(kk * 2 + ch) * 64 + lane) * 8);

    // t=0 neighbor indices, issued before staging (hidden under it)
    int idxc[KNBR];
    {
        const int n0 = wbase + c;
        const bool v = (n0 < N);
#pragma unroll
        for (int kk = 0; kk < KNBR; ++kk) {
            if (kk == 3) idxc[kk] = v ? n0 : -1;         // center: nbr[3,n] == n
            else         idxc[kk] = v ? nbr[(size_t)kk * N + n0] : -1;
        }
    }

    // stage grid window: coalesced f32 reads, cvt, padded LDS bf16 rows
    for (int e = threadIdx.x; e < WIN * 4; e += NT) {
        int row = e >> 2, seg = e & 3;
        int gr = win_lo + row;
        if (gr >= 0 && gr < N) {
            const float* gp = grid + gbase + (size_t)gr * 32 + seg * 8;
            float4 x0 = *(const float4*)gp;
            float4 x1 = *(const float4*)(gp + 4);
            short8 vv;
            vv[0] = (short)f2bf(x0.x); vv[1] = (short)f2bf(x0.y);
            vv[2] = (short)f2bf(x0.z); vv[3] = (short)f2bf(x0.w);
            vv[4] = (short)f2bf(x1.x); vv[5] = (short)f2bf(x1.y);
            vv[6] = (short)f2bf(x1.z); vv[7] = (short)f2bf(x1.w);
            *(short8*)(glds + row * LROW + seg * 8) = vv;
        }
    }
    __syncthreads();

    const float bc0 = bias[c];
    const float bc1 = bias[16 + c];

#pragma unroll
    for (int t = 0; t < 4; ++t) {
        // prefetch next sub-tile's indices before this tile's MFMA cluster
        int idxn[KNBR];
        if (t < 3) {
            const int n1 = wbase + (t + 1) * 16 + c;
            const bool v = (n1 < N);
#pragma unroll
            for (int kk = 0; kk < KNBR; ++kk) {
                if (kk == 3) idxn[kk] = v ? n1 : -1;
                else         idxn[kk] = v ? nbr[(size_t)kk * N + n1] : -1;
            }
        }

        f32x4 acc0 = {0.f, 0.f, 0.f, 0.f};
        f32x4 acc1 = {0.f, 0.f, 0.f, 0.f};
#pragma unroll
        for (int kk = 0; kk < KNBR; ++kk) {
            short8 a = {0, 0, 0, 0, 0, 0, 0, 0};
            int id = idxc[kk];
            if (id >= 0)
                a = *(const short8*)(glds + (size_t)(id - win_lo) * LROW + g * 8);
            acc0 = __builtin_amdgcn_mfma_f32_16x16x32_bf16(a, bw[kk][0], acc0, 0, 0, 0);
            acc1 = __builtin_amdgcn_mfma_f32_16x16x32_bf16(a, bw[kk][1], acc1, 0, 0, 0);
        }

        const int row_base = wbase + t * 16 + g * 4;
#pragma unroll
        for (int r = 0; r < 4; ++r) {
            int row = row_base + r;
            if (row < N) {
                float* op = out + gbase + (size_t)row * 32;
                __builtin_nontemporal_store(acc0[r] + bc0, op + c);
                __builtin_nontemporal_store(acc1[r] + bc1, op + 16 + c);
            }
        }

        if (t < 3) {
#pragma unroll
            for (int kk = 0; kk < KNBR; ++kk) idxc[kk] = idxn[kk];
        }
    }
}

extern "C" void kernel_launch(void* const* d_in, const int* in_sizes, int n_in,
                              void* d_out, int out_size, void* d_ws, size_t ws_size,
                              hipStream_t stream)
{
    const float* grid  = (const float*)d_in[0];
    const float* dyn   = (const float*)d_in[1];
    const int*   nbr   = (const int*)d_in[2];
    const float* Wdyn  = (const float*)d_in[3];
    const float* Wstat = (const float*)d_in[4];
    const float* bias  = (const float*)d_in[5];
    float* out = (float*)d_out;

    const int N = in_sizes[2] / KNBR;               // 27361
    const int B = in_sizes[0] / (N * IN);           // 32

    unsigned short* Wp = (unsigned short*)d_ws;     // B*7*1024 bf16 = 458752 B
    pack_weights<<<B * KNBR, 256, 0, stream>>>(dyn, Wdyn, Wstat, Wp);

    dim3 grd((N + ROWS - 1) / ROWS, B);
    hexconv_fused<<<grd, NT, 0, stream>>>(grid, nbr, Wp, bias, out, N);
}